// Round 4
// baseline (280.871 us; speedup 1.0000x reference)
//
#include <hip/hip_runtime.h>
#include <math.h>

// ---------------------------------------------------------------------------
// PatientDistillation: three losses.
//  out[0] = train_loss (CE over s_logits/labels)
//  out[1] = soft_loss  (KL(batchmean) at temperature T, * T^2)
//  out[2] = distill_loss (sum over rows of k smallest same-label sq dists / D)
//
// R11 post-mortem: 2-deep prefetch neutral-to-worse (93->97); zred+short-tail
// net -7 us loss -> both reverted. Model: total = gemm + ~170 us (harness
// resets + ~25 us tail). Lever = gemm delivered bytes x rate.
// R12: asymmetric tile TM=128 (S, delivered ONCE) x TN=256 (T, delivered 2x):
// 288 MB instead of 450 MB. 512-thr blocks (8 waves, 2x4 of 64x64 = acc[4][4]
// per wave, R9's proven wave shape), 60 KB LDS, 2 blocks/CU (in-flight
// loads/CU identical to R9's 3x256x8), gz=256 -> grid 512 = 2/CU. Keep:
// 1-deep register prefetch, raw-barrier (no vmcnt drain), LP=40 pitch,
// XCD-aware decode, no atomics in GEMM.
// ---------------------------------------------------------------------------

#define TMS 128         // S rows per block (each S row staged once per z)
#define TNT 256         // T rows per block (full width; staged by both blocks)
#define BK 32           // k-elems per iter; one 16x16x32 MFMA k-step
#define LP 40           // shorts per LDS row (80 B): ~2-way banks, 16B-aligned
#define STHS (TMS * LP) // 5120 shorts = 10 KB
#define STHT (TNT * LP) // 10240 shorts = 20 KB
#define STAGE (STHS + STHT) // 30 KB per stage; x2 = 60 KB

typedef __attribute__((ext_vector_type(8))) short short8;   // 8 bf16 = 4 VGPR
typedef __attribute__((ext_vector_type(4))) float f32x4;

__device__ inline unsigned pack_bf16(float a, float b) {
    // round-to-nearest-even f32 -> bf16, packed pair
    unsigned ua = __float_as_uint(a), ub = __float_as_uint(b);
    ua = (ua + 0x7fffu + ((ua >> 16) & 1u)) >> 16;
    ub = (ub + 0x7fffu + ((ub >> 16) & 1u)) >> 16;
    return (ua & 0xffffu) | (ub << 16);
}

// Barrier that does NOT drain outstanding global (vmcnt) loads.
// lgkmcnt(0) covers this wave's LDS writes/reads before arrival -> the
// single-barrier double-buffer invariant holds exactly as __syncthreads.
__device__ inline void barrier_keep_vmem() {
    asm volatile("s_waitcnt lgkmcnt(0)" ::: "memory");
    __builtin_amdgcn_s_barrier();
    asm volatile("" ::: "memory");
}

// ---------------- MFMA GEMM: dot partials + norm partials ------------------
// grid = mt*nt*gz blocks of 512 thr. Per block: S-tile 128 rows, T-tile 256
// rows. 8 waves in 2x4: wave (wm,wn) owns 64x64 output = 4x4 frags of
// 16x16x32 bf16. Register dbuf: stage(p) | issue loads(p+1) | raw-barrier |
// compute(p); single barrier per iter race-free (a wave staging buffer b at
// iter it has passed the barrier at it-1, after all waves read b at it-2).
__global__ __launch_bounds__(512, 4) void gemm_dot_kernel(const float* __restrict__ S,
                                                          const float* __restrict__ T,
                                                          float* __restrict__ part,   // [gz][B*B]
                                                          float* __restrict__ spart,  // [gz][B]
                                                          float* __restrict__ tpart,  // [gz][B]
                                                          int* __restrict__ counter,
                                                          int B, int K, int KC,
                                                          int mt, int nt, int gz) {
    __shared__ __align__(16) unsigned short smem[2 * STAGE];  // 60 KB static

    const int tid   = threadIdx.x;
    const int blk   = blockIdx.x;
    const int tiles = mt * nt;   // 2

    if (blk == 0 && tid == 0) *counter = 0;   // replaces memset dispatch

    // ---- XCD-aware decode: same-z blocks co-resident on one XCD ----
    int z, mn;
    if ((gz & 7) == 0) {
        const int xcd  = blk & 7;
        const int slot = blk >> 3;
        const int zpx  = gz >> 3;       // z-values per XCD
        mn = slot % tiles;
        z  = xcd * zpx + slot / tiles;
    } else {
        z  = blk / tiles;
        mn = blk % tiles;
    }
    const int i0 = (mn / nt) * TMS;
    const int j0 = (mn % nt) * TNT;
    const int kbeg  = z * KC;
    const int iters = KC / BK;

    const int lane = tid & 63;
    const int wid  = tid >> 6;      // 0..7
    const int wm   = wid >> 2;      // 0..1 : 64-row band within 128
    const int wn   = wid & 3;       // 0..3 : 64-col band within 256
    const int l15  = lane & 15;
    const int quad = lane >> 4;

    // ---- staging coords ----
    // S: 4 threads/row, 8 floats each. T: 2 threads/row, 16 floats each.
    const int rS = tid >> 2, hS = tid & 3;      // rS 0..127
    const int rT = tid >> 1, hT = tid & 1;      // rT 0..255
    int gi = i0 + rS; if (gi >= B) gi = B - 1;  // harmless duplicate
    int gj = j0 + rT; if (gj >= B) gj = B - 1;
    const float* srcS = S + (size_t)gi * K + kbeg + hS * 8;
    const float* srcT = T + (size_t)gj * K + kbeg + hT * 16;
    const int woffS = rS * LP + hS * 8;         // shorts; 16B-aligned
    const int woffT = rT * LP + hT * 16;

    // ---- frag read offsets (shorts) ----
    int aoff[4], boff[4];
    #pragma unroll
    for (int t = 0; t < 4; ++t) {
        aoff[t] = (wm * 64 + t * 16 + l15) * LP + quad * 8;
        boff[t] = (wn * 64 + t * 16 + l15) * LP + quad * 8;
    }

    const bool doS = ((mn % nt) == 0);   // j0==0 blocks own their S-row norms
    const bool doT = ((mn / nt) == 0);   // i0==0 blocks own T norms

    f32x4 acc[4][4] = {};
    float pns = 0.f, pnt = 0.f;

    // ---- prologue loads (iter 0): S 2x f32x4, T 4x f32x4 per thread ----
    f32x4 sA0 = *(const f32x4*)(srcS + 0);
    f32x4 sA1 = *(const f32x4*)(srcS + 4);
    f32x4 tB0 = *(const f32x4*)(srcT + 0);
    f32x4 tB1 = *(const f32x4*)(srcT + 4);
    f32x4 tB2 = *(const f32x4*)(srcT + 8);
    f32x4 tB3 = *(const f32x4*)(srcT + 12);

    for (int it = 0; it < iters; ++it) {
        unsigned short* As = smem + (it & 1) * STAGE;
        unsigned short* Bs = As + STHS;

        // ---- norms (block-uniform branches), pack, stage to LDS ----
        if (doS)
            pns += sA0.x*sA0.x + sA0.y*sA0.y + sA0.z*sA0.z + sA0.w*sA0.w
                 + sA1.x*sA1.x + sA1.y*sA1.y + sA1.z*sA1.z + sA1.w*sA1.w;
        if (doT)
            pnt += tB0.x*tB0.x + tB0.y*tB0.y + tB0.z*tB0.z + tB0.w*tB0.w
                 + tB1.x*tB1.x + tB1.y*tB1.y + tB1.z*tB1.z + tB1.w*tB1.w
                 + tB2.x*tB2.x + tB2.y*tB2.y + tB2.z*tB2.z + tB2.w*tB2.w
                 + tB3.x*tB3.x + tB3.y*tB3.y + tB3.z*tB3.z + tB3.w*tB3.w;
        uint4 pa  = make_uint4(pack_bf16(sA0.x, sA0.y), pack_bf16(sA0.z, sA0.w),
                               pack_bf16(sA1.x, sA1.y), pack_bf16(sA1.z, sA1.w));
        uint4 pb0 = make_uint4(pack_bf16(tB0.x, tB0.y), pack_bf16(tB0.z, tB0.w),
                               pack_bf16(tB1.x, tB1.y), pack_bf16(tB1.z, tB1.w));
        uint4 pb1 = make_uint4(pack_bf16(tB2.x, tB2.y), pack_bf16(tB2.z, tB2.w),
                               pack_bf16(tB3.x, tB3.y), pack_bf16(tB3.z, tB3.w));
        *(uint4*)&As[woffS]     = pa;
        *(uint4*)&Bs[woffT]     = pb0;
        *(uint4*)&Bs[woffT + 8] = pb1;

        // ---- issue next iter's loads (stay in flight across barrier+compute)
        if (it + 1 < iters) {
            const float* nS = srcS + (it + 1) * BK;
            const float* nT = srcT + (it + 1) * BK;
            sA0 = *(const f32x4*)(nS + 0);
            sA1 = *(const f32x4*)(nS + 4);
            tB0 = *(const f32x4*)(nT + 0);
            tB1 = *(const f32x4*)(nT + 4);
            tB2 = *(const f32x4*)(nT + 8);
            tB3 = *(const f32x4*)(nT + 12);
        }

        // lgkmcnt(0) + raw s_barrier: vmcnt prefetch NOT drained (R9)
        barrier_keep_vmem();

        // ---- compute: 4x4 frags of 16x16x32 ----
        short8 bfr[4];
        #pragma unroll
        for (int ni = 0; ni < 4; ++ni)
            bfr[ni] = *(const short8*)&Bs[boff[ni]];
        #pragma unroll
        for (int mi = 0; mi < 4; ++mi) {
            short8 afr = *(const short8*)&As[aoff[mi]];
            #pragma unroll
            for (int ni = 0; ni < 4; ++ni)
                acc[mi][ni] = __builtin_amdgcn_mfma_f32_16x16x32_bf16(
                    afr, bfr[ni], acc[mi][ni], 0, 0, 0);
        }
    }

    // ---- dot partials: plain stores ----
    // C/D layout (16x16x32): col = lane&15, row = (lane>>4)*4 + reg
    float* outp = part + (size_t)z * B * B;
    #pragma unroll
    for (int mi = 0; mi < 4; ++mi) {
        #pragma unroll
        for (int ni = 0; ni < 4; ++ni) {
            #pragma unroll
            for (int rr = 0; rr < 4; ++rr) {
                const int ig = i0 + wm * 64 + mi * 16 + quad * 4 + rr;
                const int jg = j0 + wn * 64 + ni * 16 + l15;
                if (ig < B && jg < B)
                    outp[(size_t)ig * B + jg] = acc[mi][ni][rr];
            }
        }
    }

    // ---- norm partials ----
    if (doS) {  // 4 threads/row: xor-1 + xor-2 combine
        float v = pns;
        v += __shfl_xor(v, 1, 64);
        v += __shfl_xor(v, 2, 64);
        if ((tid & 3) == 0 && i0 + rS < B) spart[(size_t)z * B + i0 + rS] = v;
    }
    if (doT) {  // 2 threads/row
        float v = pnt + __shfl_xor(pnt, 1, 64);
        if ((tid & 1) == 0 && j0 + rT < B) tpart[(size_t)z * B + j0 + rT] = v;
    }
}

// ---------------- tail: z-reduce + norms + topk + CE/KL, one kernel --------
// grid = B blocks; block i handles row i. Thread j reduces part[:,i,j] with
// unroll-8 pipelined loads. Last block to finish finalizes out[0..2].
__global__ __launch_bounds__(256) void tail_kernel(const float* __restrict__ part,
                                                   const float* __restrict__ spart,
                                                   const float* __restrict__ tpart,
                                                   const float* __restrict__ t_logits,
                                                   const float* __restrict__ s_logits,
                                                   const int* __restrict__ labels,
                                                   const int* __restrict__ kp,
                                                   const int* __restrict__ tp,
                                                   float* __restrict__ rowsum,
                                                   int* __restrict__ counter,
                                                   float* __restrict__ out,
                                                   int B, int K, int NL, int gz) {
    const int i   = blockIdx.x;
    const int tid = threadIdx.x;
    const size_t BB = (size_t)B * B;

    __shared__ float svals[256];
    __shared__ float rv[256];
    __shared__ int   ri[256];
    __shared__ float red[4];
    __shared__ float snv;
    __shared__ int   lastf;

    // ---- s_nrm_i: threads cooperate over z
    float sp = 0.f;
    for (int z = tid; z < gz; z += 256) sp += spart[(size_t)z * B + i];
    #pragma unroll
    for (int off = 32; off > 0; off >>= 1) sp += __shfl_down(sp, off, 64);
    if ((tid & 63) == 0) red[tid >> 6] = sp;
    __syncthreads();
    if (tid == 0) snv = red[0] + red[1] + red[2] + red[3];
    __syncthreads();
    const float sn = snv;

    // ---- dt_j, tn_j: unroll-8 z-reduction (pipelined independent loads)
    float v = INFINITY;
    if (tid < B) {
        const float* pp = part + (size_t)i * B + tid;
        const float* tq = tpart + tid;
        float d0=0.f,d1=0.f,d2=0.f,d3=0.f,d4=0.f,d5=0.f,d6=0.f,d7=0.f;
        float tn = 0.f;
        int z = 0;
        for (; z + 8 <= gz; z += 8) {
            d0 += pp[(size_t)(z+0) * BB];
            d1 += pp[(size_t)(z+1) * BB];
            d2 += pp[(size_t)(z+2) * BB];
            d3 += pp[(size_t)(z+3) * BB];
            d4 += pp[(size_t)(z+4) * BB];
            d5 += pp[(size_t)(z+5) * BB];
            d6 += pp[(size_t)(z+6) * BB];
            d7 += pp[(size_t)(z+7) * BB];
            tn += tq[(size_t)(z+0) * B] + tq[(size_t)(z+1) * B]
                + tq[(size_t)(z+2) * B] + tq[(size_t)(z+3) * B]
                + tq[(size_t)(z+4) * B] + tq[(size_t)(z+5) * B]
                + tq[(size_t)(z+6) * B] + tq[(size_t)(z+7) * B];
        }
        float dt = ((d0+d1)+(d2+d3)) + ((d4+d5)+(d6+d7));
        for (; z < gz; ++z) {
            dt += pp[(size_t)z * BB];
            tn += tq[(size_t)z * B];
        }
        if (labels[i] == labels[tid])
            v = fmaxf(sn + tn - 2.0f * dt, 0.0f);
    }
    svals[tid] = v;
    __syncthreads();

    // ---- top-k smallest via LDS tournament
    const int k = kp[0];
    float sum = 0.0f;
    for (int it = 0; it < k; ++it) {
        rv[tid] = svals[tid];
        ri[tid] = tid;
        __syncthreads();
        #pragma unroll
        for (int s = 128; s > 0; s >>= 1) {
            if (tid < s) {
                if (rv[tid + s] < rv[tid]) { rv[tid] = rv[tid + s]; ri[tid] = ri[tid + s]; }
            }
            __syncthreads();
        }
        if (tid == 0) {
            if (rv[0] < 3.0e38f) sum += rv[0];
            svals[ri[0]] = INFINITY;
        }
        __syncthreads();
    }

    if (tid == 0) {
        rowsum[i] = sum;
        __threadfence();
        lastf = (atomicAdd(counter, 1) == B - 1) ? 1 : 0;
    }
    __syncthreads();
    if (!lastf) return;

    // ---- last block: finalize all three losses ----
    __threadfence();
    const float Tv = (float)tp[0];
    float rs = (tid < B) ? rowsum[tid] : 0.f;
    float ce = 0.0f, kl = 0.0f;
    for (int s = tid; s < B; s += 256) {
        const float* sl = s_logits + (size_t)s * NL;
        const float* tl = t_logits + (size_t)s * NL;
        float mx = -INFINITY;
        for (int c = 0; c < NL; ++c) mx = fmaxf(mx, sl[c]);
        float se = 0.0f;
        for (int c = 0; c < NL; ++c) se += expf(sl[c] - mx);
        ce += logf(se) + mx - sl[labels[s]];

        float mxs = -INFINITY, mxt = -INFINITY;
        for (int c = 0; c < NL; ++c) {
            mxs = fmaxf(mxs, sl[c] / Tv);
            mxt = fmaxf(mxt, tl[c] / Tv);
        }
        float ses = 0.0f, set = 0.0f;
        for (int c = 0; c < NL; ++c) {
            ses += expf(sl[c] / Tv - mxs);
            set += expf(tl[c] / Tv - mxt);
        }
        float lses = logf(ses) + mxs;
        float lset = logf(set) + mxt;
        for (int c = 0; c < NL; ++c) {
            float lst = tl[c] / Tv - lset;
            float ls  = sl[c] / Tv - lses;
            kl += expf(lst) * (lst - ls);
        }
    }
    #pragma unroll
    for (int off = 32; off > 0; off >>= 1) {
        ce += __shfl_down(ce, off, 64);
        kl += __shfl_down(kl, off, 64);
        rs += __shfl_down(rs, off, 64);
    }
    __shared__ float wce[4], wkl[4], wrs[4];
    if ((tid & 63) == 0) { wce[tid >> 6] = ce; wkl[tid >> 6] = kl; wrs[tid >> 6] = rs; }
    __syncthreads();
    if (tid == 0) {
        out[0] = (wce[0] + wce[1] + wce[2] + wce[3]) / (float)B;
        out[1] = (wkl[0] + wkl[1] + wkl[2] + wkl[3]) / (float)B * Tv * Tv;
        out[2] = (wrs[0] + wrs[1] + wrs[2] + wrs[3]) / (float)K;
    }
}

// ---------------------------------------------------------------------------
extern "C" void kernel_launch(void* const* d_in, const int* in_sizes, int n_in,
                              void* d_out, int out_size, void* d_ws, size_t ws_size,
                              hipStream_t stream) {
    const float* t_logits = (const float*)d_in[0];
    const float* s_logits = (const float*)d_in[1];
    const float* t_feat   = (const float*)d_in[2];
    const float* s_feat   = (const float*)d_in[3];
    const int*   labels   = (const int*)d_in[4];
    const int*   kp       = (const int*)d_in[5];
    const int*   tp       = (const int*)d_in[6];
    float* out = (float*)d_out;

    const int B  = in_sizes[4];          // 256
    const int NL = in_sizes[0] / B;      // 2
    const int K  = in_sizes[2] / B;      // S*H = 98304
    const size_t BB = (size_t)B * B;

    const int mt = (B + TMS - 1) / TMS;  // 2
    const int nt = (B + TNT - 1) / TNT;  // 1

    // split-K: prefer gz=256 (grid = 2*256 = 512 = 2 blocks/CU); need
    // K % (gz*BK) == 0 and workspace fit.
    const size_t avail = ws_size / 4;
    const int cands[] = {256, 192, 128, 96, 64, 48, 32, 24, 16, 12, 8, 6, 4, 2, 1};
    int gz = 1;
    for (int ci = 0; ci < 15; ++ci) {
        const int g = cands[ci];
        if (K % (g * BK) != 0) continue;
        const size_t need = (size_t)g * BB + 2 * (size_t)g * B + B + 1;
        if (need <= avail) { gz = g; break; }
    }
    const int KC = K / gz;

    float* ws      = (float*)d_ws;
    float* part    = ws;                          // gz * B*B
    float* spart   = part + (size_t)gz * BB;      // gz * B
    float* tpart   = spart + (size_t)gz * B;      // gz * B
    float* rowsum  = tpart + (size_t)gz * B;      // B
    int*   counter = (int*)(rowsum + B);          // 1

    const int grid = mt * nt * gz;
    gemm_dot_kernel<<<grid, 512, 0, stream>>>(s_feat, t_feat, part,
                                              spart, tpart, counter,
                                              B, K, KC, mt, nt, gz);

    tail_kernel<<<B, 256, 0, stream>>>(part, spart, tpart, t_logits, s_logits,
                                       labels, kp, tp, rowsum, counter, out,
                                       B, K, NL, gz);
}